// Round 14
// baseline (250.913 us; speedup 1.0000x reference)
//
#include <hip/hip_runtime.h>

typedef unsigned short u16;
typedef __attribute__((ext_vector_type(8))) short short8;   // 8 x bf16 (4 VGPRs) MFMA A/B frag
typedef __attribute__((ext_vector_type(4))) float f32x4;    // MFMA C/D frag

__device__ __forceinline__ u16 f2b(float f) {               // f32 -> bf16 RNE
    union { float f; unsigned u; } v; v.f = f;
    unsigned u = v.u;
    u += 0x7fffu + ((u >> 16) & 1u);
    return (u16)(u >> 16);
}
__device__ __forceinline__ float b2f(u16 s) {
    union { unsigned u; float f; } v; v.u = ((unsigned)s) << 16;
    return v.f;
}
__device__ __forceinline__ void gload_lds16(const u16* g, u16* l) {
    __builtin_amdgcn_global_load_lds((const __attribute__((address_space(1))) void*)g,
                                     (__attribute__((address_space(3))) void*)l, 16, 0, 0);
}
// sortable packed key: (monotone f32 bits & ~0xFF) | (255-idx); max = best value, lowest idx on tie
__device__ __forceinline__ unsigned packkey(float f, int idx) {
    union { float f; unsigned u; } q; q.f = f;
    unsigned u = q.u;
    unsigned s = u ^ (unsigned)(((int)u >> 31) | 0x80000000);
    return (s & 0xFFFFFF00u) | (unsigned)(255 - idx);
}

// Sizes: B=2, N=1024, T=2048 tokens, H=8, D=256, DK=128, NK=256 keys, TOPK=16, NUM_KV=65536.

// ---------------- K0: all input prep in one launch (5 jobs) ----------------
__global__ __launch_bounds__(256) void prep_all(
    const float* __restrict__ x, const float* __restrict__ pkk, const float* __restrict__ wqpk,
    const float* __restrict__ wq, const float* __restrict__ wo,
    u16* __restrict__ xhi, u16* __restrict__ xlo,
    u16* __restrict__ pkthi, u16* __restrict__ pktlo,
    u16* __restrict__ wqpkhi, u16* __restrict__ wqpklo,
    u16* __restrict__ wq_t, u16* __restrict__ wo_t)
{
    int job = blockIdx.y, tid = threadIdx.x;
    __shared__ float t[64][65];
    if (job < 3) {
        for (int i = blockIdx.x * 256 + tid; i < 524288; i += 256 * 256) {
            if (job == 0) {
                float v = x[i];
                u16 hi = f2b(v); xhi[i] = hi; xlo[i] = f2b(v - b2f(hi));
            } else if (job == 1) {
                // pkt[p][h][key][d] = pk_keys[p][key][h][d]; d innermost both sides -> coalesced
                int d = i & 127, key = (i >> 7) & 255, h = (i >> 15) & 7, p = i >> 18;
                float v = pkk[(((p << 8) + key) * 8 + h) * 128 + d];
                u16 hi = f2b(v); pkthi[i] = hi; pktlo[i] = f2b(v - b2f(hi));
            } else {
                float v = wqpk[i];                              // [256][2048] straight split
                u16 hi = f2b(v); wqpkhi[i] = hi; wqpklo[i] = f2b(v - b2f(hi));
            }
        }
        return;
    }
    if (blockIdx.x >= 128) return;
    const float* in = (job == 3) ? wq : wo;
    int R = (job == 4) ? 2048 : 256;      // output leading dim
    int C = (job == 4) ? 256 : 2048;      // input cols
    int CT = C >> 6;
    int tile = blockIdx.x;
    int tr = tile / CT, tc = tile % CT;
    #pragma unroll
    for (int p = 0; p < 16; p++) {
        int row = p * 4 + (tid >> 6), col = tid & 63;
        t[row][col] = in[(size_t)(tr * 64 + row) * C + tc * 64 + col];
    }
    __syncthreads();
    #pragma unroll
    for (int p = 0; p < 16; p++) {
        int row = p * 4 + (tid >> 6), col = tid & 63;
        float v = t[col][row];
        size_t o = (size_t)(tc * 64 + row) * R + tr * 64 + col;
        if (job == 3) wq_t[o] = f2b(v);
        else          wo_t[o] = f2b(v);
    }
}

// ---------------- 64-tile bf16x3 MFMA GEMM, z = p*8+h; writes hi/lo bf16 pair ----------------
// MT[(p,h,key)][c] = sum_d pkt[p,h,key,d] * Wq_pk[c,(p,h,d)]
__global__ __launch_bounds__(256) void gemm_x3(
    const u16* __restrict__ ahi, const u16* __restrict__ alo, int aZp, int aZh, int lda,
    const u16* __restrict__ bhi, const u16* __restrict__ blo, int bZp, int bZh, int ldb,
    u16* __restrict__ c0v, u16* __restrict__ c1v, int cZp, int cZh, int ldc, int K)
{
    int z = blockIdx.z, zp = z >> 3, zh = z & 7;
    size_t aoff = (size_t)zp * aZp + (size_t)zh * aZh;
    size_t boff = (size_t)zp * bZp + (size_t)zh * bZh;
    ahi += aoff; alo += aoff; bhi += boff; blo += boff;
    size_t cb = (size_t)zp * cZp + (size_t)zh * cZh;
    int m0 = blockIdx.x * 64, n0 = blockIdx.y * 64;
    int tid = threadIdx.x, lane = tid & 63, wid = tid >> 6;
    int wr = wid >> 1, wc = wid & 1, l15 = lane & 15, cg = lane >> 4;
    __shared__ __align__(16) u16 ash[64][40], asl[64][40], bsh[64][40], bsl[64][40];
    f32x4 acc[2][2];
    #pragma unroll
    for (int m = 0; m < 2; m++)
        #pragma unroll
        for (int n = 0; n < 2; n++) acc[m][n] = (f32x4){0.f, 0.f, 0.f, 0.f};
    int rs = tid >> 2, qs = tid & 3;
    for (int k0 = 0; k0 < K; k0 += 32) {
        __syncthreads();
        *(uint4*)&ash[rs][qs * 8] = *(const uint4*)(ahi + (size_t)(m0 + rs) * lda + k0 + qs * 8);
        *(uint4*)&asl[rs][qs * 8] = *(const uint4*)(alo + (size_t)(m0 + rs) * lda + k0 + qs * 8);
        *(uint4*)&bsh[rs][qs * 8] = *(const uint4*)(bhi + (size_t)(n0 + rs) * ldb + k0 + qs * 8);
        *(uint4*)&bsl[rs][qs * 8] = *(const uint4*)(blo + (size_t)(n0 + rs) * ldb + k0 + qs * 8);
        __syncthreads();
        short8 ah[2], al[2], bh[2], bl[2];
        #pragma unroll
        for (int m = 0; m < 2; m++) {
            ah[m] = *(const short8*)&ash[wr * 32 + m * 16 + l15][cg * 8];
            al[m] = *(const short8*)&asl[wr * 32 + m * 16 + l15][cg * 8];
        }
        #pragma unroll
        for (int n = 0; n < 2; n++) {
            bh[n] = *(const short8*)&bsh[wc * 32 + n * 16 + l15][cg * 8];
            bl[n] = *(const short8*)&bsl[wc * 32 + n * 16 + l15][cg * 8];
        }
        #pragma unroll
        for (int m = 0; m < 2; m++)
            #pragma unroll
            for (int n = 0; n < 2; n++) {
                acc[m][n] = __builtin_amdgcn_mfma_f32_16x16x32_bf16(al[m], bh[n], acc[m][n], 0, 0, 0);
                acc[m][n] = __builtin_amdgcn_mfma_f32_16x16x32_bf16(ah[m], bl[n], acc[m][n], 0, 0, 0);
                acc[m][n] = __builtin_amdgcn_mfma_f32_16x16x32_bf16(ah[m], bh[n], acc[m][n], 0, 0, 0);
            }
    }
    #pragma unroll
    for (int m = 0; m < 2; m++)
        #pragma unroll
        for (int n = 0; n < 2; n++)
            #pragma unroll
            for (int r = 0; r < 4; r++) {
                int row = m0 + wr * 32 + m * 16 + cg * 4 + r;
                int col = n0 + wc * 32 + n * 16 + l15;
                float v = acc[m][n][r];
                u16 hi = f2b(v);
                c0v[cb + (size_t)row * ldc + col] = hi;
                c1v[cb + (size_t)row * ldc + col] = f2b(v - b2f(hi));
            }
}

// ---------------- 128x128-tile MFMA GEMM body (global_load_lds staging) ----------------
template<int NX, int OUT_BF16>
__device__ __forceinline__ void gemm128_body(
    u16 (*sm)[128][32],
    const u16* __restrict__ ahi, const u16* __restrict__ alo, int lda,
    const u16* __restrict__ bhi, const u16* __restrict__ blo, int ldb,
    void* __restrict__ Cv, int ldc, int K, float alpha, int m0, int n0)
{
    int tid = threadIdx.x, lane = tid & 63, wid = tid >> 6;
    int wr = wid >> 1, wc = wid & 1, l15 = lane & 15, cg = lane >> 4;
    f32x4 acc[4][4];
    #pragma unroll
    for (int m = 0; m < 4; m++)
        #pragma unroll
        for (int n = 0; n < 4; n++) acc[m][n] = (f32x4){0.f, 0.f, 0.f, 0.f};
    int wbase = tid & ~63;
    for (int k0 = 0; k0 < K; k0 += 32) {
        __syncthreads();
        #pragma unroll
        for (int i = 0; i < 2; i++) {
            int f16 = i * 256 + tid;
            int r = f16 >> 2, c = f16 & 3;
            int cs = (c ^ (r & 3)) * 8;
            u16* lbase_a = &sm[0][0][0] + (size_t)(i * 256 + wbase) * 8;
            gload_lds16(ahi + (size_t)(m0 + r) * lda + k0 + cs, lbase_a);
            u16* lbase_b = &sm[2][0][0] + (size_t)(i * 256 + wbase) * 8;
            gload_lds16(bhi + (size_t)(n0 + r) * ldb + k0 + cs, lbase_b);
            if (NX == 3) {
                u16* lbase_al = &sm[1][0][0] + (size_t)(i * 256 + wbase) * 8;
                gload_lds16(alo + (size_t)(m0 + r) * lda + k0 + cs, lbase_al);
                u16* lbase_bl = &sm[3][0][0] + (size_t)(i * 256 + wbase) * 8;
                gload_lds16(blo + (size_t)(n0 + r) * ldb + k0 + cs, lbase_bl);
            }
        }
        __syncthreads();
        short8 ah[4], bh[4], al[4], bl[4];
        #pragma unroll
        for (int m = 0; m < 4; m++) {
            int r = wr * 64 + m * 16 + l15;
            int cp = (cg ^ (r & 3)) * 8;
            ah[m] = *(const short8*)&sm[0][r][cp];
            if (NX == 3) al[m] = *(const short8*)&sm[1][r][cp];
        }
        #pragma unroll
        for (int n = 0; n < 4; n++) {
            int r = wc * 64 + n * 16 + l15;
            int cp = (cg ^ (r & 3)) * 8;
            bh[n] = *(const short8*)&sm[2][r][cp];
            if (NX == 3) bl[n] = *(const short8*)&sm[3][r][cp];
        }
        if (NX == 3) {
            #pragma unroll
            for (int m = 0; m < 4; m++)
                #pragma unroll
                for (int n = 0; n < 4; n++)
                    acc[m][n] = __builtin_amdgcn_mfma_f32_16x16x32_bf16(al[m], bh[n], acc[m][n], 0, 0, 0);
            #pragma unroll
            for (int m = 0; m < 4; m++)
                #pragma unroll
                for (int n = 0; n < 4; n++)
                    acc[m][n] = __builtin_amdgcn_mfma_f32_16x16x32_bf16(ah[m], bl[n], acc[m][n], 0, 0, 0);
        }
        #pragma unroll
        for (int m = 0; m < 4; m++)
            #pragma unroll
            for (int n = 0; n < 4; n++)
                acc[m][n] = __builtin_amdgcn_mfma_f32_16x16x32_bf16(ah[m], bh[n], acc[m][n], 0, 0, 0);
    }
    #pragma unroll
    for (int m = 0; m < 4; m++)
        #pragma unroll
        for (int n = 0; n < 4; n++)
            #pragma unroll
            for (int r = 0; r < 4; r++) {
                int row = m0 + wr * 64 + m * 16 + cg * 4 + r;
                int col = n0 + wc * 64 + n * 16 + l15;
                float v = acc[m][n][r] * alpha;
                if (OUT_BF16) ((u16*)Cv)[(size_t)row * ldc + col] = f2b(v);
                else          ((float*)Cv)[(size_t)row * ldc + col] = v;
            }
}

// ---------------- merged sims (bf16x3) + q (bf16) GEMM launch: y<32 -> sims, else -> q ----------------
__global__ __launch_bounds__(256) void gemm128_dual(
    const u16* __restrict__ xhi, const u16* __restrict__ xlo,
    const u16* __restrict__ mthi, const u16* __restrict__ mtlo,
    const u16* __restrict__ wq_t, float* __restrict__ sims, u16* __restrict__ q_b)
{
    __shared__ __align__(16) u16 sm[4][128][32];
    int m0 = blockIdx.x * 128;
    int y = blockIdx.y;
    if (y < 32)
        gemm128_body<3, 0>(sm, xhi, xlo, 256, mthi, mtlo, 256, sims, 4096, 256, 1.f, m0, y * 128);
    else
        gemm128_body<1, 1>(sm, xhi, xhi, 256, wq_t, wq_t, 256, q_b, 2048, 256, 0.0625f, m0, (y - 32) * 128);
}

// ---------------- fused two-stage top-16 + softmax + weighted gather. 1 wave per (h,t), h-major ----------------
__global__ __launch_bounds__(256) void topkgather_kernel(
    const float* __restrict__ sims, const float* __restrict__ ktab, const float* __restrict__ vtab,
    u16* __restrict__ kg, u16* __restrict__ vg)
{
    int wid = threadIdx.x >> 6, lane = threadIdx.x & 63;
    int unit = blockIdx.x * 4 + wid;   // h-major: h = unit>>11, t = unit & 2047
    int h = unit >> 11, t = unit & 2047;
    __shared__ float lv[4][2][16];
    __shared__ int   li[4][2][16];
    __shared__ float sv[4][16];
    __shared__ int   si[4][16];
    __shared__ float fwv[4][16];
    __shared__ int   gix[4][16];
    // stage 1: per-p top-16 of 256
    #pragma unroll
    for (int p = 0; p < 2; p++) {
        const float* sp = sims + (size_t)t * 4096 + p * 2048 + h * 256;
        float s[4]; unsigned k4[4];
        #pragma unroll
        for (int j = 0; j < 4; j++) { s[j] = sp[j * 64 + lane]; k4[j] = packkey(s[j], j * 64 + lane); }
        for (int it = 0; it < 16; ++it) {
            unsigned best = k4[0];
            #pragma unroll
            for (int j = 1; j < 4; j++) best = max(best, k4[j]);
            #pragma unroll
            for (int off = 1; off < 64; off <<= 1) {
                unsigned o = (unsigned)__shfl_xor((int)best, off, 64);
                best = max(best, o);
            }
            int idx = 255 - (int)(best & 255u);
            if (lane == (idx & 63)) {
                int myj = idx >> 6;
                #pragma unroll
                for (int j = 0; j < 4; j++)
                    if (myj == j) { lv[wid][p][it] = s[j]; k4[j] = 0u; }   // static index
            }
            if (lane == 0) li[wid][p][it] = idx;
        }
    }
    __syncthreads();
    // stage 2: 16x16 cartesian sums, top-16
    float c[4]; unsigned kc[4];
    #pragma unroll
    for (int j = 0; j < 4; j++) {
        int cc = j * 64 + lane;
        c[j] = lv[wid][0][cc >> 4] + lv[wid][1][cc & 15];
        kc[j] = packkey(c[j], cc);
    }
    for (int it = 0; it < 16; ++it) {
        unsigned best = kc[0];
        #pragma unroll
        for (int j = 1; j < 4; j++) best = max(best, kc[j]);
        #pragma unroll
        for (int off = 1; off < 64; off <<= 1) {
            unsigned o = (unsigned)__shfl_xor((int)best, off, 64);
            best = max(best, o);
        }
        int idx = 255 - (int)(best & 255u);
        if (lane == (idx & 63)) {
            int myj = idx >> 6;
            #pragma unroll
            for (int j = 0; j < 4; j++)
                if (myj == j) { sv[wid][it] = c[j]; kc[j] = 0u; }          // static index
        }
        if (lane == 0) si[wid][it] = idx;
    }
    __syncthreads();
    // softmax over the 16 selected (descending -> sv[0] is the max)
    if (lane < 16) {
        float myv = sv[wid][lane];
        int cc = si[wid][lane];
        float v0 = sv[wid][0];
        float e = __expf(myv - v0);
        float ssum = e;
        #pragma unroll
        for (int off = 1; off < 16; off <<= 1) ssum += __shfl_xor(ssum, off, 16);
        int gi = li[wid][0][cc >> 4] + (li[wid][1][cc & 15] << 8) + (h << 16);
        fwv[wid][lane] = e / ssum;
        gix[wid][lane] = gi;
    }
    __syncthreads();
    // gather: all 64 lanes, float4 per lane
    int b = t >> 10, n = t & 1023;
    int d4 = lane * 4;
    float4 aK = {0.f, 0.f, 0.f, 0.f}, aV = {0.f, 0.f, 0.f, 0.f};
    #pragma unroll
    for (int r = 0; r < 16; r++) {
        float wgt = fwv[wid][r];
        size_t row = (size_t)gix[wid][r];
        float4 kv = *(const float4*)(ktab + row * 256 + d4);
        float4 vv = *(const float4*)(vtab + row * 256 + d4);
        aK.x += wgt * kv.x; aK.y += wgt * kv.y; aK.z += wgt * kv.z; aK.w += wgt * kv.w;
        aV.x += wgt * vv.x; aV.y += wgt * vv.y; aV.z += wgt * vv.z; aV.w += wgt * vv.w;
    }
    size_t o = ((size_t)(b * 8 + h) * 1024 + n) * 256 + d4;   // [bh][n][d]
    ushort4 ko = {f2b(aK.x), f2b(aK.y), f2b(aK.z), f2b(aK.w)};
    ushort4 vo = {f2b(aV.x), f2b(aV.y), f2b(aV.z), f2b(aV.w)};
    *(ushort4*)(kg + o) = ko;
    *(ushort4*)(vg + o) = vo;
}

// ---------------- bf16 MFMA GEMM, z-split-K (Wo) ----------------
__global__ __launch_bounds__(256) void gemm_bt(
    const u16* __restrict__ A, int aZ, int lda,
    const u16* __restrict__ BT, int bZ, int ldb,
    float* __restrict__ Cv, size_t cZ, int ldc,
    int K, float alpha)
{
    int z = blockIdx.z;
    A  += (size_t)z * aZ;
    BT += (size_t)z * bZ;
    size_t cb = (size_t)z * cZ;
    int m0 = blockIdx.x * 64, n0 = blockIdx.y * 64;
    int tid = threadIdx.x, lane = tid & 63, wid = tid >> 6;
    int wr = wid >> 1, wc = wid & 1, l15 = lane & 15, cg = lane >> 4;
    __shared__ __align__(16) u16 as_[64][40];
    __shared__ __align__(16) u16 bs_[64][40];
    f32x4 acc[2][2];
    #pragma unroll
    for (int m = 0; m < 2; m++)
        #pragma unroll
        for (int n = 0; n < 2; n++) acc[m][n] = (f32x4){0.f, 0.f, 0.f, 0.f};
    int rs = tid >> 2, qs = tid & 3;
    for (int k0 = 0; k0 < K; k0 += 32) {
        __syncthreads();
        *(uint4*)&as_[rs][qs * 8] = *(const uint4*)(A  + (size_t)(m0 + rs) * lda + k0 + qs * 8);
        *(uint4*)&bs_[rs][qs * 8] = *(const uint4*)(BT + (size_t)(n0 + rs) * ldb + k0 + qs * 8);
        __syncthreads();
        short8 af[2], bf[2];
        #pragma unroll
        for (int m = 0; m < 2; m++) af[m] = *(const short8*)&as_[wr * 32 + m * 16 + l15][cg * 8];
        #pragma unroll
        for (int n = 0; n < 2; n++) bf[n] = *(const short8*)&bs_[wc * 32 + n * 16 + l15][cg * 8];
        #pragma unroll
        for (int m = 0; m < 2; m++)
            #pragma unroll
            for (int n = 0; n < 2; n++)
                acc[m][n] = __builtin_amdgcn_mfma_f32_16x16x32_bf16(af[m], bf[n], acc[m][n], 0, 0, 0);
    }
    #pragma unroll
    for (int m = 0; m < 2; m++)
        #pragma unroll
        for (int n = 0; n < 2; n++)
            #pragma unroll
            for (int r = 0; r < 4; r++) {
                int row = m0 + wr * 32 + m * 16 + cg * 4 + r;
                int col = n0 + wc * 32 + n * 16 + l15;
                Cv[cb + (size_t)row * ldc + col] = acc[m][n][r] * alpha;
            }
}

// ---------------- reduce 2 split-K partials -> f32 out ----------------
__global__ __launch_bounds__(256) void reduce2_kernel(const float* __restrict__ part, float* __restrict__ out)
{
    int i = (blockIdx.x * 256 + threadIdx.x) * 4;
    float4 a = *(const float4*)(part + i);
    float4 b = *(const float4*)(part + 524288 + i);
    float4 s = {a.x + b.x, a.y + b.y, a.z + b.z, a.w + b.w};
    *(float4*)(out + i) = s;
}

// ---------------- K5: transpose v [bh][n][d] -> [bh][d][n] ----------------
__global__ __launch_bounds__(256) void vtrans_kernel(const u16* __restrict__ vg, u16* __restrict__ vtg)
{
    int u = blockIdx.x;                  // 16 bh * 4 dtiles * 16 ntiles
    int bh = u >> 6, dt4 = (u >> 4) & 3, nt = u & 15;
    __shared__ float tile[64][65];
    int tid = threadIdx.x;
    #pragma unroll
    for (int p = 0; p < 16; p++) {
        int flat = p * 256 + tid; int rr = flat >> 6, cc = flat & 63;
        tile[rr][cc] = b2f(vg[((size_t)bh * 1024 + nt * 64 + rr) * 256 + dt4 * 64 + cc]);
    }
    __syncthreads();
    #pragma unroll
    for (int p = 0; p < 16; p++) {
        int flat = p * 256 + tid; int od = flat >> 6, on = flat & 63;
        vtg[((size_t)bh * 256 + dt4 * 64 + od) * 1024 + nt * 64 + on] = f2b(tile[on][od]);
    }
}

// ---------------- K6: causal flash attention, 8 waves / block, Q-tile 128, kv-chunk 64 ----------------
// Grid 16bh x 8 i-tiles = 128 blocks, 512 threads. Wave w owns q-rows i0+w*16..+15.
// Single-buffer K/V staged via global_load_lds (linear dest, pre-swizzled source), 2 barriers/chunk.
// K/V re-read traffic halved vs Q-tile 64 (sum(2it+2) = 72 chunks/bh vs 136).
__global__ __launch_bounds__(512) void attn_kernel(
    const u16* __restrict__ qb, const u16* __restrict__ kg, const u16* __restrict__ vtg,
    u16* __restrict__ attb)
{
    int bid = blockIdx.x;
    int bh = bid >> 3, it8 = bid & 7;
    int b = bh >> 3, h = bh & 7;
    int i0 = it8 * 128;
    int tid = threadIdx.x, lane = tid & 63, wid = tid >> 6;   // wid 0..7
    int l15 = lane & 15, cg = lane >> 4;

    __shared__ __align__(16) char ksm[64 * 512];      // K chunk [64][256] bf16, swizzled slot g^(r&7)
    __shared__ __align__(16) char vts[256 * 128];     // V^T chunk [256][64] bf16, swizzled slot g^(d&7)
    __shared__ __align__(16) u16  pls[8][16][72];     // per-wave P [16 rows][64 cols], pad 72

    const u16* kbase = kg  + (size_t)bh * 1024 * 256;
    const u16* vbase = vtg + (size_t)bh * 256 * 1024;
    int wuni = tid & ~63;                              // wave-uniform chunk base

    // stage chunk j0 (2048 16B-chunks each for K and V^T over 512 threads -> 4 passes each)
    auto stage = [&](int j0) {
        #pragma unroll
        for (int u4 = 0; u4 < 4; ++u4) {
            int c = u4 * 512 + tid;                    // K chunk idx in [0,2048)
            int r = c >> 5, gpos = c & 31;
            u16* lb = (u16*)ksm + (size_t)(u4 * 512 + wuni) * 8;
            gload_lds16(kbase + (size_t)(j0 + r) * 256 + ((gpos ^ (r & 7)) << 3), lb);
        }
        #pragma unroll
        for (int u4 = 0; u4 < 4; ++u4) {
            int c = u4 * 512 + tid;                    // V chunk idx in [0,2048)
            int d = c >> 3, gpos = c & 7;
            u16* lb = (u16*)vts + (size_t)(u4 * 512 + wuni) * 8;
            gload_lds16(vbase + (size_t)d * 1024 + j0 + ((gpos ^ (d & 7)) << 3), lb);
        }
    };

    int rmin = i0 + wid * 16;                          // this wave's first q-row
    short8 qf[8];
    const u16* qrow = qb + (size_t)(b * 1024 + rmin + l15) * 2048 + h * 256 + cg * 8;
    #pragma unroll
    for (int kc = 0; kc < 8; kc++) qf[kc] = *(const short8*)(qrow + kc * 32);

    f32x4 of[16];
    #pragma unroll
    for (int dt = 0; dt < 16; dt++) of[dt] = (f32x4){0.f, 0.f, 0.f, 0.f};
    float m[4] = {-1e30f, -1e30f, -1e30f, -1e30f};
    float l[4] = {0.f, 0.f, 0.f, 0.f};

    int nch = 2 * it8 + 2;

    for (int jc = 0; jc < nch; ++jc) {
        int j0 = jc * 64;
        __syncthreads();                               // prev compute done reading LDS
        stage(j0);
        __syncthreads();                               // vmcnt drained -> chunk ready

        f32x4 c[4];
        #pragma unroll
        for (int ct = 0; ct < 4; ct++) c[ct] = (f32x4){0.f, 0.f, 0.f, 0.f};
        #pragma unroll
        for (int kc = 0; kc < 8; kc++) {
            int g = kc * 4 + cg;
            #pragma unroll
            for (int ct = 0; ct < 4; ct++) {
                int r = ct * 16 + l15;
                short8 bfrag = *(const short8*)(ksm + r * 512 + ((g ^ (r & 7)) << 4));
                c[ct] = __builtin_amdgcn_mfma_f32_16x16x32_bf16(qf[kc], bfrag, c[ct], 0, 0, 0);
            }
        }
        // causal mask: only chunks overlapping/above this wave's rows (global row/col compare)
        if (j0 + 63 > rmin) {
            #pragma unroll
            for (int ct = 0; ct < 4; ct++)
                #pragma unroll
                for (int rr = 0; rr < 4; rr++)
                    if (j0 + ct * 16 + l15 > rmin + cg * 4 + rr) c[ct][rr] = -1e30f;
        }
        float es[4];
        #pragma unroll
        for (int rr = 0; rr < 4; rr++) {
            float mr = fmaxf(fmaxf(c[0][rr], c[1][rr]), fmaxf(c[2][rr], c[3][rr]));
            #pragma unroll
            for (int off = 1; off < 16; off <<= 1) mr = fmaxf(mr, __shfl_xor(mr, off, 16));
            float mn = fmaxf(m[rr], mr);
            float rsum = 0.f;
            #pragma unroll
            for (int ct = 0; ct < 4; ct++) {
                float p = __expf(c[ct][rr] - mn);
                c[ct][rr] = p; rsum += p;
            }
            #pragma unroll
            for (int off = 1; off < 16; off <<= 1) rsum += __shfl_xor(rsum, off, 16);
            es[rr] = __expf(m[rr] - mn);
            l[rr] = l[rr] * es[rr] + rsum;
            m[rr] = mn;
        }
        #pragma unroll
        for (int rr = 0; rr < 4; rr++)
            #pragma unroll
            for (int ct = 0; ct < 4; ct++)
                pls[wid][cg * 4 + rr][ct * 16 + l15] = f2b(c[ct][rr]);
        #pragma unroll
        for (int dt = 0; dt < 16; dt++)
            #pragma unroll
            for (int rr = 0; rr < 4; rr++) of[dt][rr] *= es[rr];
        short8 pa0 = *(const short8*)&pls[wid][l15][cg * 8];
        short8 pa1 = *(const short8*)&pls[wid][l15][32 + cg * 8];
        #pragma unroll
        for (int dt = 0; dt < 16; ++dt) {
            int row = dt * 16 + l15;
            short8 b0 = *(const short8*)(vts + row * 128 + ((cg       ^ (row & 7)) << 4));
            short8 b1 = *(const short8*)(vts + row * 128 + (((4 + cg) ^ (row & 7)) << 4));
            of[dt] = __builtin_amdgcn_mfma_f32_16x16x32_bf16(pa0, b0, of[dt], 0, 0, 0);
            of[dt] = __builtin_amdgcn_mfma_f32_16x16x32_bf16(pa1, b1, of[dt], 0, 0, 0);
        }
    }
    float rl[4];
    #pragma unroll
    for (int rr = 0; rr < 4; rr++) rl[rr] = 1.f / l[rr];
    u16* orow = attb + (size_t)(b * 1024 + rmin) * 2048 + h * 256;
    #pragma unroll
    for (int dt = 0; dt < 16; dt++)
        #pragma unroll
        for (int rr = 0; rr < 4; rr++)
            orow[(size_t)(cg * 4 + rr) * 2048 + dt * 16 + l15] = f2b(of[dt][rr] * rl[rr]);
}

// ---------------- launcher ----------------
extern "C" void kernel_launch(void* const* d_in, const int* in_sizes, int n_in,
                              void* d_out, int out_size, void* d_ws, size_t ws_size,
                              hipStream_t stream) {
    (void)in_sizes; (void)n_in; (void)out_size; (void)ws_size;
    const float* x    = (const float*)d_in[0];
    const float* wqpk = (const float*)d_in[1];
    const float* pkk  = (const float*)d_in[2];
    const float* wq   = (const float*)d_in[3];
    const float* ktab = (const float*)d_in[4];
    const float* vtab = (const float*)d_in[5];
    const float* wo   = (const float*)d_in[6];
    float* out = (float*)d_out;

    char* w = (char*)d_ws;
    const size_t MB = 1u << 20;
    u16*   xhi      = (u16*)(w + 0 * MB);    // [2048][256]
    u16*   xlo      = (u16*)(w + 1 * MB);
    u16*   wqpkhi   = (u16*)(w + 2 * MB);    // [256][2048]
    u16*   wqpklo   = (u16*)(w + 3 * MB);
    u16*   wq_t     = (u16*)(w + 4 * MB);    // [2048][256]
    u16*   wo_t     = (u16*)(w + 5 * MB);    // [256][2048]
    u16*   pkthi    = (u16*)(w + 6 * MB);    // [2][8][256][128]
    u16*   pktlo    = (u16*)(w + 7 * MB);
    u16*   mthi     = (u16*)(w + 8 * MB);    // [4096][256] (2 MB each)
    u16*   mtlo     = (u16*)(w + 10 * MB);
    u16*   q_b      = (u16*)(w + 12 * MB);   // [2048][2048] (8 MB), pre-scaled 1/16
    float* sims     = (float*)(w + 20 * MB); // [2048][4096] f32 (32 MB) -> ends at 52 MB
    u16*   kg       = (u16*)(w + 52 * MB);   // [16][1024][256] (8 MB)
    u16*   vg       = (u16*)(w + 60 * MB);
    u16*   vtg      = (u16*)(w + 68 * MB);   // [16][256][1024]
    u16*   attb     = (u16*)(w + 76 * MB);   // [2048][2048]
    float* wo_part  = (float*)(w + 84 * MB); // [2][2048][256] f32 (4 MB) -> 88 MB total

    prep_all<<<dim3(256, 5), 256, 0, stream>>>(x, pkk, wqpk, wq, wo,
                                               xhi, xlo, pkthi, pktlo, wqpkhi, wqpklo, wq_t, wo_t);
    // MT[(p,h,key)][c] = sum_d pkt[p,h,key,d] * Wq_pk[c,(p,h,d)]  -> hi/lo split, z = p*8+h
    gemm_x3<<<dim3(4, 4, 16), 256, 0, stream>>>(pkthi, pktlo, 262144, 32768, 128,
                                                wqpkhi, wqpklo, 1024, 128, 2048,
                                                mthi, mtlo, 524288, 65536, 256, 128);
    // merged: sims[t][(p,h,k)] = x . MT^T (bf16x3) and q = (x @ Wq)/16 (bf16), one launch
    gemm128_dual<<<dim3(16, 48), 256, 0, stream>>>(xhi, xlo, mthi, mtlo, wq_t, sims, q_b);
    // fused: two-stage top-16 + softmax + weighted gather -> kg, vg  (h-major for L3 locality)
    topkgather_kernel<<<4096, 256, 0, stream>>>(sims, ktab, vtab, kg, vg);
    vtrans_kernel<<<1024, 256, 0, stream>>>(vg, vtg);
    attn_kernel<<<128, 512, 0, stream>>>(q_b, kg, vtg, attb);
    // out = att @ Wo, split-K=2 (grid 256 blocks = 1/CU), then reduce
    gemm_bt<<<dim3(32, 4, 2), 256, 0, stream>>>(attb, 1024, 2048, wo_t, 1024, 2048,
                                                wo_part, 524288, 256, 1024, 1.f);
    reduce2_kernel<<<512, 256, 0, stream>>>(wo_part, out);
}

// Round 15
// 238.633 us; speedup vs baseline: 1.0515x; 1.0515x over previous
//
#include <hip/hip_runtime.h>

typedef unsigned short u16;
typedef __attribute__((ext_vector_type(8))) short short8;   // 8 x bf16 (4 VGPRs) MFMA A/B frag
typedef __attribute__((ext_vector_type(4))) float f32x4;    // MFMA C/D frag

__device__ __forceinline__ u16 f2b(float f) {               // f32 -> bf16 RNE
    union { float f; unsigned u; } v; v.f = f;
    unsigned u = v.u;
    u += 0x7fffu + ((u >> 16) & 1u);
    return (u16)(u >> 16);
}
__device__ __forceinline__ float b2f(u16 s) {
    union { unsigned u; float f; } v; v.u = ((unsigned)s) << 16;
    return v.f;
}
__device__ __forceinline__ void gload_lds16(const u16* g, u16* l) {
    __builtin_amdgcn_global_load_lds((const __attribute__((address_space(1))) void*)g,
                                     (__attribute__((address_space(3))) void*)l, 16, 0, 0);
}
// sortable packed key: (monotone f32 bits & ~0xFF) | (255-idx); max = best value, lowest idx on tie
__device__ __forceinline__ unsigned packkey(float f, int idx) {
    union { float f; unsigned u; } q; q.f = f;
    unsigned u = q.u;
    unsigned s = u ^ (unsigned)(((int)u >> 31) | 0x80000000);
    return (s & 0xFFFFFF00u) | (unsigned)(255 - idx);
}

// Sizes: B=2, N=1024, T=2048 tokens, H=8, D=256, DK=128, NK=256 keys, TOPK=16, NUM_KV=65536.

// ---------------- K0: all input prep in one launch (5 jobs) ----------------
__global__ __launch_bounds__(256) void prep_all(
    const float* __restrict__ x, const float* __restrict__ pkk, const float* __restrict__ wqpk,
    const float* __restrict__ wq, const float* __restrict__ wo,
    u16* __restrict__ xhi, u16* __restrict__ xlo,
    u16* __restrict__ pkthi, u16* __restrict__ pktlo,
    u16* __restrict__ wqpkhi, u16* __restrict__ wqpklo,
    u16* __restrict__ wq_t, u16* __restrict__ wo_t)
{
    int job = blockIdx.y, tid = threadIdx.x;
    __shared__ float t[64][65];
    if (job < 3) {
        for (int i = blockIdx.x * 256 + tid; i < 524288; i += 256 * 256) {
            if (job == 0) {
                float v = x[i];
                u16 hi = f2b(v); xhi[i] = hi; xlo[i] = f2b(v - b2f(hi));
            } else if (job == 1) {
                // pkt[p][h][key][d] = pk_keys[p][key][h][d]; d innermost both sides -> coalesced
                int d = i & 127, key = (i >> 7) & 255, h = (i >> 15) & 7, p = i >> 18;
                float v = pkk[(((p << 8) + key) * 8 + h) * 128 + d];
                u16 hi = f2b(v); pkthi[i] = hi; pktlo[i] = f2b(v - b2f(hi));
            } else {
                float v = wqpk[i];                              // [256][2048] straight split
                u16 hi = f2b(v); wqpkhi[i] = hi; wqpklo[i] = f2b(v - b2f(hi));
            }
        }
        return;
    }
    if (blockIdx.x >= 128) return;
    const float* in = (job == 3) ? wq : wo;
    int R = (job == 4) ? 2048 : 256;      // output leading dim
    int C = (job == 4) ? 256 : 2048;      // input cols
    int CT = C >> 6;
    int tile = blockIdx.x;
    int tr = tile / CT, tc = tile % CT;
    #pragma unroll
    for (int p = 0; p < 16; p++) {
        int row = p * 4 + (tid >> 6), col = tid & 63;
        t[row][col] = in[(size_t)(tr * 64 + row) * C + tc * 64 + col];
    }
    __syncthreads();
    #pragma unroll
    for (int p = 0; p < 16; p++) {
        int row = p * 4 + (tid >> 6), col = tid & 63;
        float v = t[col][row];
        size_t o = (size_t)(tc * 64 + row) * R + tr * 64 + col;
        if (job == 3) wq_t[o] = f2b(v);
        else          wo_t[o] = f2b(v);
    }
}

// ---------------- 64-tile bf16x3 MFMA GEMM, z = p*8+h; writes hi/lo bf16 pair ----------------
// MT[(p,h,key)][c] = sum_d pkt[p,h,key,d] * Wq_pk[c,(p,h,d)]
__global__ __launch_bounds__(256) void gemm_x3(
    const u16* __restrict__ ahi, const u16* __restrict__ alo, int aZp, int aZh, int lda,
    const u16* __restrict__ bhi, const u16* __restrict__ blo, int bZp, int bZh, int ldb,
    u16* __restrict__ c0v, u16* __restrict__ c1v, int cZp, int cZh, int ldc, int K)
{
    int z = blockIdx.z, zp = z >> 3, zh = z & 7;
    size_t aoff = (size_t)zp * aZp + (size_t)zh * aZh;
    size_t boff = (size_t)zp * bZp + (size_t)zh * bZh;
    ahi += aoff; alo += aoff; bhi += boff; blo += boff;
    size_t cb = (size_t)zp * cZp + (size_t)zh * cZh;
    int m0 = blockIdx.x * 64, n0 = blockIdx.y * 64;
    int tid = threadIdx.x, lane = tid & 63, wid = tid >> 6;
    int wr = wid >> 1, wc = wid & 1, l15 = lane & 15, cg = lane >> 4;
    __shared__ __align__(16) u16 ash[64][40], asl[64][40], bsh[64][40], bsl[64][40];
    f32x4 acc[2][2];
    #pragma unroll
    for (int m = 0; m < 2; m++)
        #pragma unroll
        for (int n = 0; n < 2; n++) acc[m][n] = (f32x4){0.f, 0.f, 0.f, 0.f};
    int rs = tid >> 2, qs = tid & 3;
    for (int k0 = 0; k0 < K; k0 += 32) {
        __syncthreads();
        *(uint4*)&ash[rs][qs * 8] = *(const uint4*)(ahi + (size_t)(m0 + rs) * lda + k0 + qs * 8);
        *(uint4*)&asl[rs][qs * 8] = *(const uint4*)(alo + (size_t)(m0 + rs) * lda + k0 + qs * 8);
        *(uint4*)&bsh[rs][qs * 8] = *(const uint4*)(bhi + (size_t)(n0 + rs) * ldb + k0 + qs * 8);
        *(uint4*)&bsl[rs][qs * 8] = *(const uint4*)(blo + (size_t)(n0 + rs) * ldb + k0 + qs * 8);
        __syncthreads();
        short8 ah[2], al[2], bh[2], bl[2];
        #pragma unroll
        for (int m = 0; m < 2; m++) {
            ah[m] = *(const short8*)&ash[wr * 32 + m * 16 + l15][cg * 8];
            al[m] = *(const short8*)&asl[wr * 32 + m * 16 + l15][cg * 8];
        }
        #pragma unroll
        for (int n = 0; n < 2; n++) {
            bh[n] = *(const short8*)&bsh[wc * 32 + n * 16 + l15][cg * 8];
            bl[n] = *(const short8*)&bsl[wc * 32 + n * 16 + l15][cg * 8];
        }
        #pragma unroll
        for (int m = 0; m < 2; m++)
            #pragma unroll
            for (int n = 0; n < 2; n++) {
                acc[m][n] = __builtin_amdgcn_mfma_f32_16x16x32_bf16(al[m], bh[n], acc[m][n], 0, 0, 0);
                acc[m][n] = __builtin_amdgcn_mfma_f32_16x16x32_bf16(ah[m], bl[n], acc[m][n], 0, 0, 0);
                acc[m][n] = __builtin_amdgcn_mfma_f32_16x16x32_bf16(ah[m], bh[n], acc[m][n], 0, 0, 0);
            }
    }
    #pragma unroll
    for (int m = 0; m < 2; m++)
        #pragma unroll
        for (int n = 0; n < 2; n++)
            #pragma unroll
            for (int r = 0; r < 4; r++) {
                int row = m0 + wr * 32 + m * 16 + cg * 4 + r;
                int col = n0 + wc * 32 + n * 16 + l15;
                float v = acc[m][n][r];
                u16 hi = f2b(v);
                c0v[cb + (size_t)row * ldc + col] = hi;
                c1v[cb + (size_t)row * ldc + col] = f2b(v - b2f(hi));
            }
}

// ---------------- 128x128-tile MFMA GEMM body (global_load_lds staging) ----------------
template<int NX, int OUT_BF16>
__device__ __forceinline__ void gemm128_body(
    u16 (*sm)[128][32],
    const u16* __restrict__ ahi, const u16* __restrict__ alo, int lda,
    const u16* __restrict__ bhi, const u16* __restrict__ blo, int ldb,
    void* __restrict__ Cv, int ldc, int K, float alpha, int m0, int n0)
{
    int tid = threadIdx.x, lane = tid & 63, wid = tid >> 6;
    int wr = wid >> 1, wc = wid & 1, l15 = lane & 15, cg = lane >> 4;
    f32x4 acc[4][4];
    #pragma unroll
    for (int m = 0; m < 4; m++)
        #pragma unroll
        for (int n = 0; n < 4; n++) acc[m][n] = (f32x4){0.f, 0.f, 0.f, 0.f};
    int wbase = tid & ~63;
    for (int k0 = 0; k0 < K; k0 += 32) {
        __syncthreads();
        #pragma unroll
        for (int i = 0; i < 2; i++) {
            int f16 = i * 256 + tid;
            int r = f16 >> 2, c = f16 & 3;
            int cs = (c ^ (r & 3)) * 8;
            u16* lbase_a = &sm[0][0][0] + (size_t)(i * 256 + wbase) * 8;
            gload_lds16(ahi + (size_t)(m0 + r) * lda + k0 + cs, lbase_a);
            u16* lbase_b = &sm[2][0][0] + (size_t)(i * 256 + wbase) * 8;
            gload_lds16(bhi + (size_t)(n0 + r) * ldb + k0 + cs, lbase_b);
            if (NX == 3) {
                u16* lbase_al = &sm[1][0][0] + (size_t)(i * 256 + wbase) * 8;
                gload_lds16(alo + (size_t)(m0 + r) * lda + k0 + cs, lbase_al);
                u16* lbase_bl = &sm[3][0][0] + (size_t)(i * 256 + wbase) * 8;
                gload_lds16(blo + (size_t)(n0 + r) * ldb + k0 + cs, lbase_bl);
            }
        }
        __syncthreads();
        short8 ah[4], bh[4], al[4], bl[4];
        #pragma unroll
        for (int m = 0; m < 4; m++) {
            int r = wr * 64 + m * 16 + l15;
            int cp = (cg ^ (r & 3)) * 8;
            ah[m] = *(const short8*)&sm[0][r][cp];
            if (NX == 3) al[m] = *(const short8*)&sm[1][r][cp];
        }
        #pragma unroll
        for (int n = 0; n < 4; n++) {
            int r = wc * 64 + n * 16 + l15;
            int cp = (cg ^ (r & 3)) * 8;
            bh[n] = *(const short8*)&sm[2][r][cp];
            if (NX == 3) bl[n] = *(const short8*)&sm[3][r][cp];
        }
        if (NX == 3) {
            #pragma unroll
            for (int m = 0; m < 4; m++)
                #pragma unroll
                for (int n = 0; n < 4; n++)
                    acc[m][n] = __builtin_amdgcn_mfma_f32_16x16x32_bf16(al[m], bh[n], acc[m][n], 0, 0, 0);
            #pragma unroll
            for (int m = 0; m < 4; m++)
                #pragma unroll
                for (int n = 0; n < 4; n++)
                    acc[m][n] = __builtin_amdgcn_mfma_f32_16x16x32_bf16(ah[m], bl[n], acc[m][n], 0, 0, 0);
        }
        #pragma unroll
        for (int m = 0; m < 4; m++)
            #pragma unroll
            for (int n = 0; n < 4; n++)
                acc[m][n] = __builtin_amdgcn_mfma_f32_16x16x32_bf16(ah[m], bh[n], acc[m][n], 0, 0, 0);
    }
    #pragma unroll
    for (int m = 0; m < 4; m++)
        #pragma unroll
        for (int n = 0; n < 4; n++)
            #pragma unroll
            for (int r = 0; r < 4; r++) {
                int row = m0 + wr * 64 + m * 16 + cg * 4 + r;
                int col = n0 + wc * 64 + n * 16 + l15;
                float v = acc[m][n][r] * alpha;
                if (OUT_BF16) ((u16*)Cv)[(size_t)row * ldc + col] = f2b(v);
                else          ((float*)Cv)[(size_t)row * ldc + col] = v;
            }
}

// ---------------- merged sims (bf16x3) + q (bf16) GEMM launch: y<32 -> sims, else -> q ----------------
__global__ __launch_bounds__(256) void gemm128_dual(
    const u16* __restrict__ xhi, const u16* __restrict__ xlo,
    const u16* __restrict__ mthi, const u16* __restrict__ mtlo,
    const u16* __restrict__ wq_t, float* __restrict__ sims, u16* __restrict__ q_b)
{
    __shared__ __align__(16) u16 sm[4][128][32];
    int m0 = blockIdx.x * 128;
    int y = blockIdx.y;
    if (y < 32)
        gemm128_body<3, 0>(sm, xhi, xlo, 256, mthi, mtlo, 256, sims, 4096, 256, 1.f, m0, y * 128);
    else
        gemm128_body<1, 1>(sm, xhi, xhi, 256, wq_t, wq_t, 256, q_b, 2048, 256, 0.0625f, m0, (y - 32) * 128);
}

// ---------------- fused two-stage top-16 + softmax + weighted gather. 1 wave per (h,t), h-major ----------------
// h-major block order: same-h blocks adjacent -> per-h table region (~52 MB) stays L3-resident.
__global__ __launch_bounds__(256) void topkgather_kernel(
    const float* __restrict__ sims, const float* __restrict__ ktab, const float* __restrict__ vtab,
    u16* __restrict__ kg, u16* __restrict__ vg)
{
    int wid = threadIdx.x >> 6, lane = threadIdx.x & 63;
    int unit = blockIdx.x * 4 + wid;   // h-major: h = unit>>11, t = unit & 2047
    int h = unit >> 11, t = unit & 2047;
    __shared__ float lv[4][2][16];
    __shared__ int   li[4][2][16];
    __shared__ float sv[4][16];
    __shared__ int   si[4][16];
    __shared__ float fwv[4][16];
    __shared__ int   gix[4][16];
    // stage 1: per-p top-16 of 256
    #pragma unroll
    for (int p = 0; p < 2; p++) {
        const float* sp = sims + (size_t)t * 4096 + p * 2048 + h * 256;
        float s[4]; unsigned k4[4];
        #pragma unroll
        for (int j = 0; j < 4; j++) { s[j] = sp[j * 64 + lane]; k4[j] = packkey(s[j], j * 64 + lane); }
        for (int it = 0; it < 16; ++it) {
            unsigned best = k4[0];
            #pragma unroll
            for (int j = 1; j < 4; j++) best = max(best, k4[j]);
            #pragma unroll
            for (int off = 1; off < 64; off <<= 1) {
                unsigned o = (unsigned)__shfl_xor((int)best, off, 64);
                best = max(best, o);
            }
            int idx = 255 - (int)(best & 255u);
            if (lane == (idx & 63)) {
                int myj = idx >> 6;
                #pragma unroll
                for (int j = 0; j < 4; j++)
                    if (myj == j) { lv[wid][p][it] = s[j]; k4[j] = 0u; }   // static index
            }
            if (lane == 0) li[wid][p][it] = idx;
        }
    }
    __syncthreads();
    // stage 2: 16x16 cartesian sums, top-16
    float c[4]; unsigned kc[4];
    #pragma unroll
    for (int j = 0; j < 4; j++) {
        int cc = j * 64 + lane;
        c[j] = lv[wid][0][cc >> 4] + lv[wid][1][cc & 15];
        kc[j] = packkey(c[j], cc);
    }
    for (int it = 0; it < 16; ++it) {
        unsigned best = kc[0];
        #pragma unroll
        for (int j = 1; j < 4; j++) best = max(best, kc[j]);
        #pragma unroll
        for (int off = 1; off < 64; off <<= 1) {
            unsigned o = (unsigned)__shfl_xor((int)best, off, 64);
            best = max(best, o);
        }
        int idx = 255 - (int)(best & 255u);
        if (lane == (idx & 63)) {
            int myj = idx >> 6;
            #pragma unroll
            for (int j = 0; j < 4; j++)
                if (myj == j) { sv[wid][it] = c[j]; kc[j] = 0u; }          // static index
        }
        if (lane == 0) si[wid][it] = idx;
    }
    __syncthreads();
    // softmax over the 16 selected (descending -> sv[0] is the max)
    if (lane < 16) {
        float myv = sv[wid][lane];
        int cc = si[wid][lane];
        float v0 = sv[wid][0];
        float e = __expf(myv - v0);
        float ssum = e;
        #pragma unroll
        for (int off = 1; off < 16; off <<= 1) ssum += __shfl_xor(ssum, off, 16);
        int gi = li[wid][0][cc >> 4] + (li[wid][1][cc & 15] << 8) + (h << 16);
        fwv[wid][lane] = e / ssum;
        gix[wid][lane] = gi;
    }
    __syncthreads();
    // gather: all 64 lanes, float4 per lane
    int b = t >> 10, n = t & 1023;
    int d4 = lane * 4;
    float4 aK = {0.f, 0.f, 0.f, 0.f}, aV = {0.f, 0.f, 0.f, 0.f};
    #pragma unroll
    for (int r = 0; r < 16; r++) {
        float wgt = fwv[wid][r];
        size_t row = (size_t)gix[wid][r];
        float4 kv = *(const float4*)(ktab + row * 256 + d4);
        float4 vv = *(const float4*)(vtab + row * 256 + d4);
        aK.x += wgt * kv.x; aK.y += wgt * kv.y; aK.z += wgt * kv.z; aK.w += wgt * kv.w;
        aV.x += wgt * vv.x; aV.y += wgt * vv.y; aV.z += wgt * vv.z; aV.w += wgt * vv.w;
    }
    size_t o = ((size_t)(b * 8 + h) * 1024 + n) * 256 + d4;   // [bh][n][d]
    ushort4 ko = {f2b(aK.x), f2b(aK.y), f2b(aK.z), f2b(aK.w)};
    ushort4 vo = {f2b(aV.x), f2b(aV.y), f2b(aV.z), f2b(aV.w)};
    *(ushort4*)(kg + o) = ko;
    *(ushort4*)(vg + o) = vo;
}

// ---------------- bf16 MFMA GEMM, z-split-K (Wo) ----------------
__global__ __launch_bounds__(256) void gemm_bt(
    const u16* __restrict__ A, int aZ, int lda,
    const u16* __restrict__ BT, int bZ, int ldb,
    float* __restrict__ Cv, size_t cZ, int ldc,
    int K, float alpha)
{
    int z = blockIdx.z;
    A  += (size_t)z * aZ;
    BT += (size_t)z * bZ;
    size_t cb = (size_t)z * cZ;
    int m0 = blockIdx.x * 64, n0 = blockIdx.y * 64;
    int tid = threadIdx.x, lane = tid & 63, wid = tid >> 6;
    int wr = wid >> 1, wc = wid & 1, l15 = lane & 15, cg = lane >> 4;
    __shared__ __align__(16) u16 as_[64][40];
    __shared__ __align__(16) u16 bs_[64][40];
    f32x4 acc[2][2];
    #pragma unroll
    for (int m = 0; m < 2; m++)
        #pragma unroll
        for (int n = 0; n < 2; n++) acc[m][n] = (f32x4){0.f, 0.f, 0.f, 0.f};
    int rs = tid >> 2, qs = tid & 3;
    for (int k0 = 0; k0 < K; k0 += 32) {
        __syncthreads();
        *(uint4*)&as_[rs][qs * 8] = *(const uint4*)(A  + (size_t)(m0 + rs) * lda + k0 + qs * 8);
        *(uint4*)&bs_[rs][qs * 8] = *(const uint4*)(BT + (size_t)(n0 + rs) * ldb + k0 + qs * 8);
        __syncthreads();
        short8 af[2], bf[2];
        #pragma unroll
        for (int m = 0; m < 2; m++) af[m] = *(const short8*)&as_[wr * 32 + m * 16 + l15][cg * 8];
        #pragma unroll
        for (int n = 0; n < 2; n++) bf[n] = *(const short8*)&bs_[wc * 32 + n * 16 + l15][cg * 8];
        #pragma unroll
        for (int m = 0; m < 2; m++)
            #pragma unroll
            for (int n = 0; n < 2; n++)
                acc[m][n] = __builtin_amdgcn_mfma_f32_16x16x32_bf16(af[m], bf[n], acc[m][n], 0, 0, 0);
    }
    #pragma unroll
    for (int m = 0; m < 2; m++)
        #pragma unroll
        for (int n = 0; n < 2; n++)
            #pragma unroll
            for (int r = 0; r < 4; r++) {
                int row = m0 + wr * 32 + m * 16 + cg * 4 + r;
                int col = n0 + wc * 32 + n * 16 + l15;
                Cv[cb + (size_t)row * ldc + col] = acc[m][n][r] * alpha;
            }
}

// ---------------- reduce 2 split-K partials -> f32 out ----------------
__global__ __launch_bounds__(256) void reduce2_kernel(const float* __restrict__ part, float* __restrict__ out)
{
    int i = (blockIdx.x * 256 + threadIdx.x) * 4;
    float4 a = *(const float4*)(part + i);
    float4 b = *(const float4*)(part + 524288 + i);
    float4 s = {a.x + b.x, a.y + b.y, a.z + b.z, a.w + b.w};
    *(float4*)(out + i) = s;
}

// ---------------- K5: transpose v [bh][n][d] -> [bh][d][n] ----------------
__global__ __launch_bounds__(256) void vtrans_kernel(const u16* __restrict__ vg, u16* __restrict__ vtg)
{
    int u = blockIdx.x;                  // 16 bh * 4 dtiles * 16 ntiles
    int bh = u >> 6, dt4 = (u >> 4) & 3, nt = u & 15;
    __shared__ float tile[64][65];
    int tid = threadIdx.x;
    #pragma unroll
    for (int p = 0; p < 16; p++) {
        int flat = p * 256 + tid; int rr = flat >> 6, cc = flat & 63;
        tile[rr][cc] = b2f(vg[((size_t)bh * 1024 + nt * 64 + rr) * 256 + dt4 * 64 + cc]);
    }
    __syncthreads();
    #pragma unroll
    for (int p = 0; p < 16; p++) {
        int flat = p * 256 + tid; int od = flat >> 6, on = flat & 63;
        vtg[((size_t)bh * 256 + dt4 * 64 + od) * 1024 + nt * 64 + on] = f2b(tile[on][od]);
    }
}

// ---------------- K6: causal flash attention, 4 waves / block, Q-tile 64, kv-chunk 64 ----------------
__global__ __launch_bounds__(256) void attn_kernel(
    const u16* __restrict__ qb, const u16* __restrict__ kg, const u16* __restrict__ vtg,
    u16* __restrict__ attb)
{
    int bid = blockIdx.x;
    int bh = bid >> 4, it = bid & 15;
    int b = bh >> 3, h = bh & 7;
    int i0 = it * 64;
    int tid = threadIdx.x, lane = tid & 63, wid = tid >> 6;
    int l15 = lane & 15, cg = lane >> 4;

    __shared__ __align__(16) char ksm[64 * 512];
    __shared__ __align__(16) char vts[256 * 128];
    __shared__ __align__(16) u16  pls[4][16][72];

    short8 qf[8];
    const u16* qrow = qb + (size_t)(b * 1024 + i0 + wid * 16 + l15) * 2048 + h * 256 + cg * 8;
    #pragma unroll
    for (int kc = 0; kc < 8; kc++) qf[kc] = *(const short8*)(qrow + kc * 32);

    f32x4 of[16];
    #pragma unroll
    for (int dt = 0; dt < 16; dt++) of[dt] = (f32x4){0.f, 0.f, 0.f, 0.f};
    float m[4] = {-1e30f, -1e30f, -1e30f, -1e30f};
    float l[4] = {0.f, 0.f, 0.f, 0.f};

    int nch = it + 1;
    const u16* kbase = kg  + (size_t)bh * 1024 * 256;
    const u16* vbase = vtg + (size_t)bh * 256 * 1024;

    for (int jc = 0; jc < nch; ++jc) {
        int j0 = jc * 64;
        __syncthreads();
        #pragma unroll
        for (int u8 = 0; u8 < 8; ++u8) {
            int flat = u8 * 256 + tid; int r = flat >> 5, g = flat & 31;
            uint4 val = *(const uint4*)(kbase + (size_t)(j0 + r) * 256 + g * 8);
            *(uint4*)(ksm + r * 512 + ((g ^ (r & 7)) << 4)) = val;
        }
        #pragma unroll
        for (int u8 = 0; u8 < 8; ++u8) {
            int flat = u8 * 256 + tid; int d = flat >> 3, g = flat & 7;
            uint4 val = *(const uint4*)(vbase + (size_t)d * 1024 + j0 + g * 8);
            *(uint4*)(vts + d * 128 + ((g ^ (d & 7)) << 4)) = val;
        }
        __syncthreads();

        f32x4 c[4];
        #pragma unroll
        for (int ct = 0; ct < 4; ct++) c[ct] = (f32x4){0.f, 0.f, 0.f, 0.f};
        #pragma unroll
        for (int kc = 0; kc < 8; kc++) {
            int g = kc * 4 + cg;
            #pragma unroll
            for (int ct = 0; ct < 4; ct++) {
                int r = ct * 16 + l15;
                short8 bfrag = *(const short8*)(ksm + r * 512 + ((g ^ (r & 7)) << 4));
                c[ct] = __builtin_amdgcn_mfma_f32_16x16x32_bf16(qf[kc], bfrag, c[ct], 0, 0, 0);
            }
        }
        if (jc == it) {
            #pragma unroll
            for (int ct = 0; ct < 4; ct++)
                #pragma unroll
                for (int rr = 0; rr < 4; rr++)
                    if (ct * 16 + l15 > wid * 16 + cg * 4 + rr) c[ct][rr] = -1e30f;
        }
        float es[4];
        #pragma unroll
        for (int rr = 0; rr < 4; rr++) {
            float mr = fmaxf(fmaxf(c[0][rr], c[1][rr]), fmaxf(c[2][rr], c[3][rr]));
            #pragma unroll
            for (int off = 1; off < 16; off <<= 1) mr = fmaxf(mr, __shfl_xor(mr, off, 16));
            float mn = fmaxf(m[rr], mr);
            float rsum = 0.f;
            #pragma unroll
            for (int ct = 0; ct < 4; ct++) {
                float p = __expf(c[ct][rr] - mn);
                c[ct][rr] = p; rsum += p;
            }
            #pragma unroll
            for (int off = 1; off < 16; off <<= 1) rsum += __shfl_xor(rsum, off, 16);
            es[rr] = __expf(m[rr] - mn);
            l[rr] = l[rr] * es[rr] + rsum;
            m[rr] = mn;
        }
        #pragma unroll
        for (int rr = 0; rr < 4; rr++)
            #pragma unroll
            for (int ct = 0; ct < 4; ct++)
                pls[wid][cg * 4 + rr][ct * 16 + l15] = f2b(c[ct][rr]);
        #pragma unroll
        for (int dt = 0; dt < 16; dt++)
            #pragma unroll
            for (int rr = 0; rr < 4; rr++) of[dt][rr] *= es[rr];
        short8 pa0 = *(const short8*)&pls[wid][l15][cg * 8];
        short8 pa1 = *(const short8*)&pls[wid][l15][32 + cg * 8];
        #pragma unroll
        for (int dt = 0; dt < 16; ++dt) {
            int row = dt * 16 + l15;
            short8 b0 = *(const short8*)(vts + row * 128 + ((cg       ^ (row & 7)) << 4));
            short8 b1 = *(const short8*)(vts + row * 128 + (((4 + cg) ^ (row & 7)) << 4));
            of[dt] = __builtin_amdgcn_mfma_f32_16x16x32_bf16(pa0, b0, of[dt], 0, 0, 0);
            of[dt] = __builtin_amdgcn_mfma_f32_16x16x32_bf16(pa1, b1, of[dt], 0, 0, 0);
        }
    }
    float rl[4];
    #pragma unroll
    for (int rr = 0; rr < 4; rr++) rl[rr] = 1.f / l[rr];
    u16* orow = attb + (size_t)(b * 1024 + i0 + wid * 16) * 2048 + h * 256;
    #pragma unroll
    for (int dt = 0; dt < 16; dt++)
        #pragma unroll
        for (int rr = 0; rr < 4; rr++)
            orow[(size_t)(cg * 4 + rr) * 2048 + dt * 16 + l15] = f2b(of[dt][rr] * rl[rr]);
}

// ---------------- launcher ----------------
extern "C" void kernel_launch(void* const* d_in, const int* in_sizes, int n_in,
                              void* d_out, int out_size, void* d_ws, size_t ws_size,
                              hipStream_t stream) {
    (void)in_sizes; (void)n_in; (void)out_size; (void)ws_size;
    const float* x    = (const float*)d_in[0];
    const float* wqpk = (const float*)d_in[1];
    const float* pkk  = (const float*)d_in[2];
    const float* wq   = (const float*)d_in[3];
    const float* ktab = (const float*)d_in[4];
    const float* vtab = (const float*)d_in[5];
    const float* wo   = (const float*)d_in[6];
    float* out = (float*)d_out;

    char* w = (char*)d_ws;
    const size_t MB = 1u << 20;
    u16*   xhi      = (u16*)(w + 0 * MB);    // [2048][256]
    u16*   xlo      = (u16*)(w + 1 * MB);
    u16*   wqpkhi   = (u16*)(w + 2 * MB);    // [256][2048]
    u16*   wqpklo   = (u16*)(w + 3 * MB);
    u16*   wq_t     = (u16*)(w + 4 * MB);    // [2048][256]
    u16*   wo_t     = (u16*)(w + 5 * MB);    // [256][2048]
    u16*   pkthi    = (u16*)(w + 6 * MB);    // [2][8][256][128]
    u16*   pktlo    = (u16*)(w + 7 * MB);
    u16*   mthi     = (u16*)(w + 8 * MB);    // [4096][256] (2 MB each)
    u16*   mtlo     = (u16*)(w + 10 * MB);
    u16*   q_b      = (u16*)(w + 12 * MB);   // [2048][2048] (8 MB), pre-scaled 1/16
    float* sims     = (float*)(w + 20 * MB); // [2048][4096] f32 (32 MB) -> ends at 52 MB
    u16*   kg       = (u16*)(w + 52 * MB);   // [16][1024][256] (8 MB)
    u16*   vg       = (u16*)(w + 60 * MB);
    u16*   vtg      = (u16*)(w + 68 * MB);   // [16][256][1024]
    u16*   attb     = (u16*)(w + 76 * MB);   // [2048][2048]
    float* wo_part  = (float*)(w + 84 * MB); // [2][2048][256] f32 (4 MB) -> 88 MB total

    prep_all<<<dim3(256, 5), 256, 0, stream>>>(x, pkk, wqpk, wq, wo,
                                               xhi, xlo, pkthi, pktlo, wqpkhi, wqpklo, wq_t, wo_t);
    // MT[(p,h,key)][c] = sum_d pkt[p,h,key,d] * Wq_pk[c,(p,h,d)]  -> hi/lo split, z = p*8+h
    gemm_x3<<<dim3(4, 4, 16), 256, 0, stream>>>(pkthi, pktlo, 262144, 32768, 128,
                                                wqpkhi, wqpklo, 1024, 128, 2048,
                                                mthi, mtlo, 524288, 65536, 256, 128);
    // merged: sims[t][(p,h,k)] = x . MT^T (bf16x3) and q = (x @ Wq)/16 (bf16), one launch
    gemm128_dual<<<dim3(16, 48), 256, 0, stream>>>(xhi, xlo, mthi, mtlo, wq_t, sims, q_b);
    // fused: two-stage top-16 + softmax + weighted gather -> kg, vg  (h-major for L3 locality)
    topkgather_kernel<<<4096, 256, 0, stream>>>(sims, ktab, vtab, kg, vg);
    vtrans_kernel<<<1024, 256, 0, stream>>>(vg, vtg);
    attn_kernel<<<256, 256, 0, stream>>>(q_b, kg, vtg, attb);
    // out = att @ Wo, split-K=2 (grid 256 blocks = 1/CU), then reduce
    gemm_bt<<<dim3(32, 4, 2), 256, 0, stream>>>(attb, 1024, 2048, wo_t, 1024, 2048,
                                                wo_part, 524288, 256, 1024, 1.f);
    reduce2_kernel<<<512, 256, 0, stream>>>(wo_part, out);
}